// Round 7
// baseline (470.185 us; speedup 1.0000x reference)
//
#include <hip/hip_runtime.h>
#include <hip/hip_bf16.h>

// GAT layer, N=8192, DIN=256, DOUT=128.
// h = x@W+bW; e_ij = leaky_relu(s_src[i]+s_dst[j]+ba); p = adj ? exp(e) : 0
// (no max-subtraction: |e| <= ~10 unmasked, fp32-safe). out_i = (sum_j p_ij h_j)/(sum_j p_ij).
//
// R14: the only lever that has ever moved gat_attn is VMEM-instruction
// count per edge (R7->R12 rows/wave 32->64: -30us; all data-placement/
// occupancy/staging changes: null). Working model: under the 2-block
// 256-reg budget the compiler has ~7 regs of load-ahead, so the ~300
// VMEM insts/wave serialize at ~L2 latency (~220cy) -> ~55us of the
// ~90us kernel. Attack both terms: 128 rows/wave (8 A-frag row-groups,
// halves B-frag loads per edge again) and launch_bounds(256,1) (512-reg
// budget: 256 AGPR acc + ~110 VGPR leaves ~140 regs of hoisting slack).
// Grid 256 = 16 row-blocks x jsplit 16 = exactly 1 block/CU. s_dst via
// LDS prologue (kills the 32 cd VMEM loads/wave). Direct B-frag loads
// (8 KB tile is L1-resident, shared by the block's 4 waves); R13's LDS
// B-staging was null (-3us) and is dropped.

#define NN 8192
#define DIN 256
#define DOUT 128
#define LOG2E 1.4426950408889634f

typedef __attribute__((ext_vector_type(8))) short short8;   // 8 bf16 = 4 VGPRs (MFMA A/B frag)
typedef __attribute__((ext_vector_type(4))) float floatx4;  // MFMA C/D frag

// ---------------- kernel 0: W [256][128] fp32 -> WT [128][256] bf16 ----------------
__global__ void prep_wt(const float* __restrict__ W, __hip_bfloat16* __restrict__ WT) {
    int e = blockIdx.x * blockDim.x + threadIdx.x;
    if (e < DIN * DOUT) {
        int k = e >> 7;
        int d = e & 127;
        WT[d * DIN + k] = __float2bfloat16(W[e]);
    }
}

// ---------------- kernel 1: h = x@W + bW (MFMA), fused s_src/s_dst; h -> hbB frag-tile layout ----------------
// hbB flat index for h-element (row i, dim d):
//   g=i>>5, k=i&31, f=d>>4, n=d&15 -> g*4096 + f*512 + (k>>3)*128 + n*8 + (k&7)
__global__ __launch_bounds__(256, 4) void gat_h(
    const float* __restrict__ x, const __hip_bfloat16* __restrict__ WT,
    const float* __restrict__ bW, const float* __restrict__ a1, const float* __restrict__ a2,
    __hip_bfloat16* __restrict__ hbB, float* __restrict__ s_src, float* __restrict__ s_dst) {
    int tid = threadIdx.x;
    int w = tid >> 6, lane = tid & 63;
    int lm = lane & 15, lq = lane >> 4;
    int i0 = blockIdx.x * 32;
    int r0 = (w >> 1) * 16;
    int c0 = (w & 1) * 64;

    __shared__ float s1s[32], s2s[32];
    if (tid < 32) { s1s[tid] = 0.f; s2s[tid] = 0.f; }
    __syncthreads();

    floatx4 acc[4] = {};
#pragma unroll
    for (int kk = 0; kk < DIN; kk += 32) {
        const float4* xp = (const float4*)&x[(size_t)(i0 + r0 + lm) * DIN + kk + lq * 8];
        float4 xa = xp[0], xb = xp[1];
        union { short8 v; __hip_bfloat16 h[8]; } af;
        af.h[0] = __float2bfloat16(xa.x); af.h[1] = __float2bfloat16(xa.y);
        af.h[2] = __float2bfloat16(xa.z); af.h[3] = __float2bfloat16(xa.w);
        af.h[4] = __float2bfloat16(xb.x); af.h[5] = __float2bfloat16(xb.y);
        af.h[6] = __float2bfloat16(xb.z); af.h[7] = __float2bfloat16(xb.w);
#pragma unroll
        for (int t = 0; t < 4; t++) {
            int d = c0 + 16 * t + lm;
            short8 bf = *(const short8*)&WT[(size_t)d * DIN + kk + lq * 8];
            acc[t] = __builtin_amdgcn_mfma_f32_16x16x32_bf16(af.v, bf, acc[t], 0, 0, 0);
        }
    }
    float s1[4] = {0.f, 0.f, 0.f, 0.f}, s2[4] = {0.f, 0.f, 0.f, 0.f};
#pragma unroll
    for (int t = 0; t < 4; t++) {
        int d = c0 + 16 * t + lm;
        int f = (c0 >> 4) + t;
        float A1 = a1[d], A2 = a2[d], B = bW[d];
#pragma unroll
        for (int r = 0; r < 4; r++) {
            int k = r0 + lq * 4 + r;
            float h = acc[t][r] + B;
            hbB[(size_t)blockIdx.x * 4096 + f * 512 + (k >> 3) * 128 + lm * 8 + (k & 7)] =
                __float2bfloat16(h);
            s1[r] += h * A1;
            s2[r] += h * A2;
        }
    }
#pragma unroll
    for (int r = 0; r < 4; r++) {
        for (int m = 1; m < 16; m <<= 1) {
            s1[r] += __shfl_xor(s1[r], m, 64);
            s2[r] += __shfl_xor(s2[r], m, 64);
        }
    }
    if (lm == 0) {
#pragma unroll
        for (int r = 0; r < 4; r++) {
            int row = r0 + lq * 4 + r;
            atomicAdd(&s1s[row], s1[r]);
            atomicAdd(&s2s[row], s2[r]);
        }
    }
    __syncthreads();
    if (tid < 32) {
        s_src[i0 + tid] = s1s[tid] * LOG2E;   // pre-scale: exp(e) = exp2(e*log2e)
        s_dst[i0 + tid] = s2s[tid] * LOG2E;
    }
}

// ---------------- kernel 2: adj -> 1-bit mask, lane-permuted layout ----------------
// Contiguous (TLB/coalesce-friendly) read of the 268 MB adj stream; byte-group
// g of each 64-byte group permuted so gat_attn lane's NJT bytes are contiguous.
template <int NJT>
__global__ void build_mask(const int* __restrict__ adj, unsigned char* __restrict__ mask) {
    size_t gid = (size_t)blockIdx.x * blockDim.x + threadIdx.x;  // 8,388,608 threads
    const int4* a = (const int4*)(adj + gid * 8);
    int4 v0 = a[0], v1 = a[1];
    unsigned int b = 0;
    b |= (v0.x != 0) ? 1u : 0u;
    b |= (v0.y != 0) ? 2u : 0u;
    b |= (v0.z != 0) ? 4u : 0u;
    b |= (v0.w != 0) ? 8u : 0u;
    b |= (v1.x != 0) ? 16u : 0u;
    b |= (v1.y != 0) ? 32u : 0u;
    b |= (v1.z != 0) ? 64u : 0u;
    b |= (v1.w != 0) ? 128u : 0u;
    unsigned int g = (unsigned int)gid & (NJT * 4 - 1);
    size_t pos = (gid & ~(size_t)(NJT * 4 - 1)) | ((g & 3) * NJT + (g >> 2));
    mask[pos] = (unsigned char)b;
}

__device__ inline short8 make_pfrag(unsigned int cm, float ssi, float4 cd0, float4 cd1,
                                    floatx4* accd, const short8 ones) {
    float p[8];
    float e;
    e = ssi + cd0.x; e = fmaxf(e, 0.01f * e); p[0] = (cm & 1u)   ? __builtin_amdgcn_exp2f(e) : 0.f;
    e = ssi + cd0.y; e = fmaxf(e, 0.01f * e); p[1] = (cm & 2u)   ? __builtin_amdgcn_exp2f(e) : 0.f;
    e = ssi + cd0.z; e = fmaxf(e, 0.01f * e); p[2] = (cm & 4u)   ? __builtin_amdgcn_exp2f(e) : 0.f;
    e = ssi + cd0.w; e = fmaxf(e, 0.01f * e); p[3] = (cm & 8u)   ? __builtin_amdgcn_exp2f(e) : 0.f;
    e = ssi + cd1.x; e = fmaxf(e, 0.01f * e); p[4] = (cm & 16u)  ? __builtin_amdgcn_exp2f(e) : 0.f;
    e = ssi + cd1.y; e = fmaxf(e, 0.01f * e); p[5] = (cm & 32u)  ? __builtin_amdgcn_exp2f(e) : 0.f;
    e = ssi + cd1.z; e = fmaxf(e, 0.01f * e); p[6] = (cm & 64u)  ? __builtin_amdgcn_exp2f(e) : 0.f;
    e = ssi + cd1.w; e = fmaxf(e, 0.01f * e); p[7] = (cm & 128u) ? __builtin_amdgcn_exp2f(e) : 0.f;
    union { short8 v; __hip_bfloat162 q[4]; } af;
    af.q[0] = __float22bfloat162_rn(make_float2(p[0], p[1]));
    af.q[1] = __float22bfloat162_rn(make_float2(p[2], p[3]));
    af.q[2] = __float22bfloat162_rn(make_float2(p[4], p[5]));
    af.q[3] = __float22bfloat162_rn(make_float2(p[6], p[7]));
    *accd = __builtin_amdgcn_mfma_f32_16x16x32_bf16(af.v, ones, *accd, 0, 0, 0);
    return af.v;
}

// ---------------- kernel 3: masked softmax-weighted GEMM, 128 rows/wave ----------------
// grid = 16 row-blocks (512 rows) x JSPLIT. Wave w: rows i0=ib*512+w*128 .. +127
// as EIGHT A-frag row-groups sharing each B-frag; all 128 dims.
// 1 block/CU, 512-reg budget: acc 8x8 floatx4 = 256 AGPR + ~110 VGPR.
template <int NJT>
__global__ __launch_bounds__(256, 1) void gat_attn(
    const unsigned char* __restrict__ mask, const float* __restrict__ s_src,
    const float* __restrict__ s_dst, const float* __restrict__ ba_p,
    const __hip_bfloat16* __restrict__ hbB,
    float* __restrict__ num, float* __restrict__ lpart) {
    int tid = threadIdx.x;
    int w = tid >> 6, lane = tid & 63;
    int lm = lane & 15, lq = lane >> 4;
    int b = blockIdx.x;
    int ib = b & 15;
    int jh = b >> 4;
    int i0 = ib * 512 + w * 128;
    int jb0 = jh * (NJT * 32);

    __shared__ float sdl[NJT * 32];      // s_dst slice (2-4 KB)

    // per-lane mask slices for 8 row-groups: NJT contiguous bytes each
    union Mr { uint4 v[NJT / 16]; unsigned int u[NJT / 4]; };
    Mr mr[8];
    const unsigned char* mrow = mask + (size_t)(i0 + lm) * (NN / 8) + jh * (NJT * 4) + lq * NJT;
#pragma unroll
    for (int rg = 0; rg < 8; rg++)
#pragma unroll
        for (int q = 0; q < NJT / 16; q++)
            mr[rg].v[q] = ((const uint4*)(mrow + (size_t)rg * 16 * (NN / 8)))[q];

    float ba = ba_p[0] * LOG2E;
    float ssi[8];
#pragma unroll
    for (int rg = 0; rg < 8; rg++) ssi[rg] = s_src[i0 + rg * 16 + lm] + ba;

    const float* sdg = s_dst + jb0;
    for (int k = tid; k < NJT * 32; k += 256) sdl[k] = sdg[k];
    __syncthreads();

    const __hip_bfloat16* hb = hbB + ((size_t)(jh * NJT) * 8) * 512 + lane * 8;

    floatx4 acc[8][8] = {};
    floatx4 accd[8] = {};
    const short8 ones = { 0x3F80, 0x3F80, 0x3F80, 0x3F80, 0x3F80, 0x3F80, 0x3F80, 0x3F80 };

#pragma unroll
    for (int t = 0; t < NJT; t++) {
        float4 cd0 = *(const float4*)&sdl[t * 32 + lq * 8];
        float4 cd1 = *(const float4*)&sdl[t * 32 + lq * 8 + 4];
        short8 af[8];
#pragma unroll
        for (int rg = 0; rg < 8; rg++) {
            unsigned int cm = (mr[rg].u[t >> 2] >> ((t & 3) * 8)) & 0xFFu;
            af[rg] = make_pfrag(cm, ssi[rg], cd0, cd1, &accd[rg], ones);
        }
        const __hip_bfloat16* hbt = hb + (size_t)t * 8 * 512;
#pragma unroll
        for (int f = 0; f < 8; f++) {
            short8 bf = *(const short8*)(hbt + f * 512);
#pragma unroll
            for (int rg = 0; rg < 8; rg++)
                acc[rg][f] = __builtin_amdgcn_mfma_f32_16x16x32_bf16(af[rg], bf, acc[rg][f], 0, 0, 0);
        }
    }

    // epilogue: C/D layout col(dim-part)=lm, row=lq*4+r. nt stores: num is only
    // consumed by gat_combine (64 MB, from HBM regardless) -- keep L2 for hbB.
    float* nb = num + ((size_t)jh * NN + i0) * DOUT;
#pragma unroll
    for (int rg = 0; rg < 8; rg++)
#pragma unroll
        for (int f = 0; f < 8; f++)
#pragma unroll
            for (int r = 0; r < 4; r++)
                __builtin_nontemporal_store(acc[rg][f][r],
                    &nb[(size_t)(rg * 16 + lq * 4 + r) * DOUT + f * 16 + lm]);
    if (lm == 0) {
#pragma unroll
        for (int rg = 0; rg < 8; rg++)
#pragma unroll
            for (int r = 0; r < 4; r++)
                lpart[(size_t)jh * NN + i0 + rg * 16 + lq * 4 + r] = accd[rg][r];
    }
}

// ---------------- kernel 4: combine partials, divide ----------------
__global__ void gat_combine(const float* __restrict__ num, const float* __restrict__ lpart,
                            float* __restrict__ out, int jsplit) {
    int gid = blockIdx.x * blockDim.x + threadIdx.x;  // 262144 threads, one float4 each
    int idx = gid * 4;
    int i = idx >> 7;
    float den = 0.f;
    for (int s = 0; s < jsplit; s++) den += lpart[(size_t)s * NN + i];
    float inv = 1.0f / den;
    floatx4 o = {0.f, 0.f, 0.f, 0.f};
    for (int s = 0; s < jsplit; s++) {
        floatx4 n = __builtin_nontemporal_load(
            (const floatx4*)&num[(size_t)s * NN * DOUT + idx]);
        o += n;
    }
    o *= inv;
    *(floatx4*)&out[idx] = o;
}

extern "C" void kernel_launch(void* const* d_in, const int* in_sizes, int n_in,
                              void* d_out, int out_size, void* d_ws, size_t ws_size,
                              hipStream_t stream) {
    const float* x  = (const float*)d_in[0];
    const int* adj  = (const int*)d_in[1];
    const float* W  = (const float*)d_in[2];
    const float* bW = (const float*)d_in[3];
    const float* a1 = (const float*)d_in[4];
    const float* a2 = (const float*)d_in[5];
    const float* ba = (const float*)d_in[6];
    float* out = (float*)d_out;

    char* ws = (char*)d_ws;
    __hip_bfloat16* hbB  = (__hip_bfloat16*)ws;                    // 2 MB   frag-tile layout
    __hip_bfloat16* WT   = (__hip_bfloat16*)(ws + 2097152);        // 64 KB
    float* s_src         = (float*)(ws + 2162688);                 // 32 KB (pre-scaled by log2e)
    float* s_dst         = (float*)(ws + 2195456);                 // 32 KB (pre-scaled by log2e)
    float* lpart         = (float*)(ws + 2228224);                 // 512 KB [<=16][8192]
    unsigned char* mask  = (unsigned char*)(ws + 2752512);         // 8 MB   permuted
    float* num           = (float*)(ws + 11141120);                // jsplit*4 MB

    int jsplit = (ws_size >= 11141120 + (size_t)16 * NN * DOUT * 4) ? 16 : 8;

    // build_mask first: keeps gat_h's outputs (hbB/s_dst) L2-warm for gat_attn.
    if (jsplit == 16) build_mask<16><<<32768, 256, 0, stream>>>(adj, mask);
    else              build_mask<32><<<32768, 256, 0, stream>>>(adj, mask);
    prep_wt<<<128, 256, 0, stream>>>(W, WT);
    gat_h<<<256, 256, 0, stream>>>(x, WT, bW, a1, a2, hbB, s_src, s_dst);
    if (jsplit == 16)
        gat_attn<16><<<256, 256, 0, stream>>>(mask, s_src, s_dst, ba, hbB, num, lpart);
    else
        gat_attn<32><<<128, 256, 0, stream>>>(mask, s_src, s_dst, ba, hbB, num, lpart);
    gat_combine<<<1024, 256, 0, stream>>>(num, lpart, out, jsplit);
}

// Round 8
// 436.819 us; speedup vs baseline: 1.0764x; 1.0764x over previous
//
#include <hip/hip_runtime.h>
#include <hip/hip_bf16.h>

// GAT layer, N=8192, DIN=256, DOUT=128.
// h = x@W+bW; e_ij = leaky_relu(s_src[i]+s_dst[j]+ba); p = adj ? exp(e) : 0
// (no max-subtraction: |e| <= ~10 unmasked, fp32-safe). out_i = (sum_j p_ij h_j)/(sum_j p_ij).
//
// R15: I-CACHE theory. gat_attn (~90us, issue-work ~15-20us) has survived
// six null/negative interventions: adj-TLB fix, 2x occupancy, zero-VGPR
// LDS staging of both adj and B-tiles (inner loop fully VMEM-free in R13:
// -3us), 512-reg budget (R14: +38). The only remaining mechanism that is
// data-, occupancy- and register-invariant is the INSTRUCTION STREAM: the
// fully-unrolled t-loop is ~4000 insts (~32 KB) -- at/over the 32 KB L1I --
// so every pass re-misses the whole body (~500 lines x ~110cy = ~23us/wave
// of front-end stall, shared by all waves; more waves don't help, which is
// exactly what R10/R11 measured). Fix: #pragma unroll 1 on the t-loop
// (body ~2.2 KB, I$-resident). Runtime t forces masks out of registers
// (dynamic mr[].u[t>>2] would go to scratch): prologue repacks each lane's
// 4 rowgroup bytes per t into one u32 in LDS (msk[w][t][lane],
// lane-contiguous, wave-private, no barrier); body does 1 ds_read_b32 +
// 4 bfe. B-frags are direct global loads (R13 proved staging them is
// unnecessary). Config reverted to best-known: 64 rows/wave, bounds(256,2),
// grid 512, jsplit 16.

#define NN 8192
#define DIN 256
#define DOUT 128
#define LOG2E 1.4426950408889634f

typedef __attribute__((ext_vector_type(8))) short short8;   // 8 bf16 = 4 VGPRs (MFMA A/B frag)
typedef __attribute__((ext_vector_type(4))) float floatx4;  // MFMA C/D frag

// ---------------- kernel 0: W [256][128] fp32 -> WT [128][256] bf16 ----------------
__global__ void prep_wt(const float* __restrict__ W, __hip_bfloat16* __restrict__ WT) {
    int e = blockIdx.x * blockDim.x + threadIdx.x;
    if (e < DIN * DOUT) {
        int k = e >> 7;
        int d = e & 127;
        WT[d * DIN + k] = __float2bfloat16(W[e]);
    }
}

// ---------------- kernel 1: h = x@W + bW (MFMA), fused s_src/s_dst; h -> hbB frag-tile layout ----------------
// hbB flat index for h-element (row i, dim d):
//   g=i>>5, k=i&31, f=d>>4, n=d&15 -> g*4096 + f*512 + (k>>3)*128 + n*8 + (k&7)
__global__ __launch_bounds__(256, 4) void gat_h(
    const float* __restrict__ x, const __hip_bfloat16* __restrict__ WT,
    const float* __restrict__ bW, const float* __restrict__ a1, const float* __restrict__ a2,
    __hip_bfloat16* __restrict__ hbB, float* __restrict__ s_src, float* __restrict__ s_dst) {
    int tid = threadIdx.x;
    int w = tid >> 6, lane = tid & 63;
    int lm = lane & 15, lq = lane >> 4;
    int i0 = blockIdx.x * 32;
    int r0 = (w >> 1) * 16;
    int c0 = (w & 1) * 64;

    __shared__ float s1s[32], s2s[32];
    if (tid < 32) { s1s[tid] = 0.f; s2s[tid] = 0.f; }
    __syncthreads();

    floatx4 acc[4] = {};
#pragma unroll
    for (int kk = 0; kk < DIN; kk += 32) {
        const float4* xp = (const float4*)&x[(size_t)(i0 + r0 + lm) * DIN + kk + lq * 8];
        float4 xa = xp[0], xb = xp[1];
        union { short8 v; __hip_bfloat16 h[8]; } af;
        af.h[0] = __float2bfloat16(xa.x); af.h[1] = __float2bfloat16(xa.y);
        af.h[2] = __float2bfloat16(xa.z); af.h[3] = __float2bfloat16(xa.w);
        af.h[4] = __float2bfloat16(xb.x); af.h[5] = __float2bfloat16(xb.y);
        af.h[6] = __float2bfloat16(xb.z); af.h[7] = __float2bfloat16(xb.w);
#pragma unroll
        for (int t = 0; t < 4; t++) {
            int d = c0 + 16 * t + lm;
            short8 bf = *(const short8*)&WT[(size_t)d * DIN + kk + lq * 8];
            acc[t] = __builtin_amdgcn_mfma_f32_16x16x32_bf16(af.v, bf, acc[t], 0, 0, 0);
        }
    }
    float s1[4] = {0.f, 0.f, 0.f, 0.f}, s2[4] = {0.f, 0.f, 0.f, 0.f};
#pragma unroll
    for (int t = 0; t < 4; t++) {
        int d = c0 + 16 * t + lm;
        int f = (c0 >> 4) + t;
        float A1 = a1[d], A2 = a2[d], B = bW[d];
#pragma unroll
        for (int r = 0; r < 4; r++) {
            int k = r0 + lq * 4 + r;
            float h = acc[t][r] + B;
            hbB[(size_t)blockIdx.x * 4096 + f * 512 + (k >> 3) * 128 + lm * 8 + (k & 7)] =
                __float2bfloat16(h);
            s1[r] += h * A1;
            s2[r] += h * A2;
        }
    }
#pragma unroll
    for (int r = 0; r < 4; r++) {
        for (int m = 1; m < 16; m <<= 1) {
            s1[r] += __shfl_xor(s1[r], m, 64);
            s2[r] += __shfl_xor(s2[r], m, 64);
        }
    }
    if (lm == 0) {
#pragma unroll
        for (int r = 0; r < 4; r++) {
            int row = r0 + lq * 4 + r;
            atomicAdd(&s1s[row], s1[r]);
            atomicAdd(&s2s[row], s2[r]);
        }
    }
    __syncthreads();
    if (tid < 32) {
        s_src[i0 + tid] = s1s[tid] * LOG2E;   // pre-scale: exp(e) = exp2(e*log2e)
        s_dst[i0 + tid] = s2s[tid] * LOG2E;
    }
}

// ---------------- kernel 2: adj -> 1-bit mask, lane-permuted layout ----------------
// Contiguous (TLB/coalesce-friendly) read of the 268 MB adj stream; byte-group
// g of each 64-byte group permuted so gat_attn lane's NJT bytes are contiguous.
template <int NJT>
__global__ void build_mask(const int* __restrict__ adj, unsigned char* __restrict__ mask) {
    size_t gid = (size_t)blockIdx.x * blockDim.x + threadIdx.x;  // 8,388,608 threads
    const int4* a = (const int4*)(adj + gid * 8);
    int4 v0 = a[0], v1 = a[1];
    unsigned int b = 0;
    b |= (v0.x != 0) ? 1u : 0u;
    b |= (v0.y != 0) ? 2u : 0u;
    b |= (v0.z != 0) ? 4u : 0u;
    b |= (v0.w != 0) ? 8u : 0u;
    b |= (v1.x != 0) ? 16u : 0u;
    b |= (v1.y != 0) ? 32u : 0u;
    b |= (v1.z != 0) ? 64u : 0u;
    b |= (v1.w != 0) ? 128u : 0u;
    unsigned int g = (unsigned int)gid & (NJT * 4 - 1);
    size_t pos = (gid & ~(size_t)(NJT * 4 - 1)) | ((g & 3) * NJT + (g >> 2));
    mask[pos] = (unsigned char)b;
}

__device__ inline short8 make_pfrag(unsigned int cm, float ssi, float4 cd0, float4 cd1,
                                    floatx4* accd, const short8 ones) {
    float p[8];
    float e;
    e = ssi + cd0.x; e = fmaxf(e, 0.01f * e); p[0] = (cm & 1u)   ? __builtin_amdgcn_exp2f(e) : 0.f;
    e = ssi + cd0.y; e = fmaxf(e, 0.01f * e); p[1] = (cm & 2u)   ? __builtin_amdgcn_exp2f(e) : 0.f;
    e = ssi + cd0.z; e = fmaxf(e, 0.01f * e); p[2] = (cm & 4u)   ? __builtin_amdgcn_exp2f(e) : 0.f;
    e = ssi + cd0.w; e = fmaxf(e, 0.01f * e); p[3] = (cm & 8u)   ? __builtin_amdgcn_exp2f(e) : 0.f;
    e = ssi + cd1.x; e = fmaxf(e, 0.01f * e); p[4] = (cm & 16u)  ? __builtin_amdgcn_exp2f(e) : 0.f;
    e = ssi + cd1.y; e = fmaxf(e, 0.01f * e); p[5] = (cm & 32u)  ? __builtin_amdgcn_exp2f(e) : 0.f;
    e = ssi + cd1.z; e = fmaxf(e, 0.01f * e); p[6] = (cm & 64u)  ? __builtin_amdgcn_exp2f(e) : 0.f;
    e = ssi + cd1.w; e = fmaxf(e, 0.01f * e); p[7] = (cm & 128u) ? __builtin_amdgcn_exp2f(e) : 0.f;
    union { short8 v; __hip_bfloat162 q[4]; } af;
    af.q[0] = __float22bfloat162_rn(make_float2(p[0], p[1]));
    af.q[1] = __float22bfloat162_rn(make_float2(p[2], p[3]));
    af.q[2] = __float22bfloat162_rn(make_float2(p[4], p[5]));
    af.q[3] = __float22bfloat162_rn(make_float2(p[6], p[7]));
    *accd = __builtin_amdgcn_mfma_f32_16x16x32_bf16(af.v, ones, *accd, 0, 0, 0);
    return af.v;
}

// ---------------- kernel 3: masked softmax-weighted GEMM, 64 rows/wave, ROLLED t-loop ----------------
// grid = 32 row-blocks (256 rows) x JSPLIT. Wave w: rows i0=ib*256+w*64 .. +63
// as FOUR A-frag row-groups sharing each B-frag; all 128 dims.
// t-loop NOT unrolled: body ~2.2 KB, I$-resident. Masks read per-t from LDS
// (packed u32: 4 rowgroup bytes), cd from LDS, B-frags direct global.
template <int NJT>
__global__ __launch_bounds__(256, 2) void gat_attn(
    const unsigned char* __restrict__ mask, const float* __restrict__ s_src,
    const float* __restrict__ s_dst, const float* __restrict__ ba_p,
    const __hip_bfloat16* __restrict__ hbB,
    float* __restrict__ num, float* __restrict__ lpart) {
    int tid = threadIdx.x;
    int w = tid >> 6, lane = tid & 63;
    int lm = lane & 15, lq = lane >> 4;
    int b = blockIdx.x;
    int ib = b & 31;
    int jh = b >> 5;
    int i0 = ib * 256 + w * 64;
    int jb0 = jh * (NJT * 32);

    __shared__ float sdl[NJT * 32];                  // s_dst slice (2-4 KB)
    __shared__ unsigned int msk[4][NJT][64];         // per-wave packed masks (16-32 KB)

    // prologue: load per-lane mask slices for 4 row-groups, repack per-t into LDS
    union Mr { uint4 v[NJT / 16]; unsigned int u[NJT / 4]; };
    Mr mr[4];
    const unsigned char* mrow = mask + (size_t)(i0 + lm) * (NN / 8) + jh * (NJT * 4) + lq * NJT;
#pragma unroll
    for (int rg = 0; rg < 4; rg++)
#pragma unroll
        for (int q = 0; q < NJT / 16; q++)
            mr[rg].v[q] = ((const uint4*)(mrow + (size_t)rg * 16 * (NN / 8)))[q];
#pragma unroll
    for (int t = 0; t < NJT; t++) {
        int sh = (t & 3) * 8;
        unsigned int pk = ((mr[0].u[t >> 2] >> sh) & 0xFFu)
                        | (((mr[1].u[t >> 2] >> sh) & 0xFFu) << 8)
                        | (((mr[2].u[t >> 2] >> sh) & 0xFFu) << 16)
                        | (((mr[3].u[t >> 2] >> sh) & 0xFFu) << 24);
        msk[w][t][lane] = pk;
    }

    float ba = ba_p[0] * LOG2E;
    float ssi[4];
#pragma unroll
    for (int rg = 0; rg < 4; rg++) ssi[rg] = s_src[i0 + rg * 16 + lm] + ba;

    const float* sdg = s_dst + jb0;
    for (int k = tid; k < NJT * 32; k += 256) sdl[k] = sdg[k];
    __syncthreads();   // sdl ready (msk is wave-private)

    const __hip_bfloat16* hb = hbB + ((size_t)(jh * NJT) * 8) * 512 + lane * 8;

    floatx4 acc[4][8] = {};
    floatx4 accd[4] = {};
    const short8 ones = { 0x3F80, 0x3F80, 0x3F80, 0x3F80, 0x3F80, 0x3F80, 0x3F80, 0x3F80 };

#pragma unroll 1
    for (int t = 0; t < NJT; t++) {
        unsigned int pk = msk[w][t][lane];
        float4 cd0 = *(const float4*)&sdl[t * 32 + lq * 8];
        float4 cd1 = *(const float4*)&sdl[t * 32 + lq * 8 + 4];
        short8 af[4];
        af[0] = make_pfrag(pk & 0xFFu, ssi[0], cd0, cd1, &accd[0], ones);
        af[1] = make_pfrag((pk >> 8) & 0xFFu, ssi[1], cd0, cd1, &accd[1], ones);
        af[2] = make_pfrag((pk >> 16) & 0xFFu, ssi[2], cd0, cd1, &accd[2], ones);
        af[3] = make_pfrag(pk >> 24, ssi[3], cd0, cd1, &accd[3], ones);
        const __hip_bfloat16* hbt = hb + (size_t)t * 8 * 512;
#pragma unroll
        for (int f = 0; f < 8; f++) {
            short8 bf = *(const short8*)(hbt + f * 512);
#pragma unroll
            for (int rg = 0; rg < 4; rg++)
                acc[rg][f] = __builtin_amdgcn_mfma_f32_16x16x32_bf16(af[rg], bf, acc[rg][f], 0, 0, 0);
        }
    }

    // epilogue: C/D layout col(dim-part)=lm, row=lq*4+r. nt stores: num is only
    // consumed by gat_combine (64 MB, from HBM regardless) -- keep L2 for hbB.
    float* nb = num + ((size_t)jh * NN + i0) * DOUT;
#pragma unroll
    for (int rg = 0; rg < 4; rg++)
#pragma unroll
        for (int f = 0; f < 8; f++)
#pragma unroll
            for (int r = 0; r < 4; r++)
                __builtin_nontemporal_store(acc[rg][f][r],
                    &nb[(size_t)(rg * 16 + lq * 4 + r) * DOUT + f * 16 + lm]);
    if (lm == 0) {
#pragma unroll
        for (int rg = 0; rg < 4; rg++)
#pragma unroll
            for (int r = 0; r < 4; r++)
                lpart[(size_t)jh * NN + i0 + rg * 16 + lq * 4 + r] = accd[rg][r];
    }
}

// ---------------- kernel 4: combine partials, divide ----------------
__global__ void gat_combine(const float* __restrict__ num, const float* __restrict__ lpart,
                            float* __restrict__ out, int jsplit) {
    int gid = blockIdx.x * blockDim.x + threadIdx.x;  // 262144 threads, one float4 each
    int idx = gid * 4;
    int i = idx >> 7;
    float den = 0.f;
    for (int s = 0; s < jsplit; s++) den += lpart[(size_t)s * NN + i];
    float inv = 1.0f / den;
    floatx4 o = {0.f, 0.f, 0.f, 0.f};
    for (int s = 0; s < jsplit; s++) {
        floatx4 n = __builtin_nontemporal_load(
            (const floatx4*)&num[(size_t)s * NN * DOUT + idx]);
        o += n;
    }
    o *= inv;
    *(floatx4*)&out[idx] = o;
}

extern "C" void kernel_launch(void* const* d_in, const int* in_sizes, int n_in,
                              void* d_out, int out_size, void* d_ws, size_t ws_size,
                              hipStream_t stream) {
    const float* x  = (const float*)d_in[0];
    const int* adj  = (const int*)d_in[1];
    const float* W  = (const float*)d_in[2];
    const float* bW = (const float*)d_in[3];
    const float* a1 = (const float*)d_in[4];
    const float* a2 = (const float*)d_in[5];
    const float* ba = (const float*)d_in[6];
    float* out = (float*)d_out;

    char* ws = (char*)d_ws;
    __hip_bfloat16* hbB  = (__hip_bfloat16*)ws;                    // 2 MB   frag-tile layout
    __hip_bfloat16* WT   = (__hip_bfloat16*)(ws + 2097152);        // 64 KB
    float* s_src         = (float*)(ws + 2162688);                 // 32 KB (pre-scaled by log2e)
    float* s_dst         = (float*)(ws + 2195456);                 // 32 KB (pre-scaled by log2e)
    float* lpart         = (float*)(ws + 2228224);                 // 512 KB [<=16][8192]
    unsigned char* mask  = (unsigned char*)(ws + 2752512);         // 8 MB   permuted
    float* num           = (float*)(ws + 11141120);                // jsplit*4 MB

    int jsplit = (ws_size >= 11141120 + (size_t)16 * NN * DOUT * 4) ? 16 : 8;

    // build_mask first: keeps gat_h's outputs (hbB/s_dst) L2-warm for gat_attn.
    if (jsplit == 16) build_mask<16><<<32768, 256, 0, stream>>>(adj, mask);
    else              build_mask<32><<<32768, 256, 0, stream>>>(adj, mask);
    prep_wt<<<128, 256, 0, stream>>>(W, WT);
    gat_h<<<256, 256, 0, stream>>>(x, WT, bW, a1, a2, hbB, s_src, s_dst);
    if (jsplit == 16)
        gat_attn<16><<<512, 256, 0, stream>>>(mask, s_src, s_dst, ba, hbB, num, lpart);
    else
        gat_attn<32><<<256, 256, 0, stream>>>(mask, s_src, s_dst, ba, hbB, num, lpart);
    gat_combine<<<1024, 256, 0, stream>>>(num, lpart, out, jsplit);
}

// Round 9
// 426.006 us; speedup vs baseline: 1.1037x; 1.0254x over previous
//
#include <hip/hip_runtime.h>
#include <hip/hip_bf16.h>

// GAT layer, N=8192, DIN=256, DOUT=128.
// h = x@W+bW; e_ij = leaky_relu(s_src[i]+s_dst[j]+ba); p = adj ? exp(e) : 0
// (no max-subtraction: |e| <= ~10 unmasked, fp32-safe). out_i = (sum_j p_ij h_j)/(sum_j p_ij).
//
// R16: nt-store theory. The ~91us mask-attn stall is invariant to
// occupancy/VMEM/registers/I$ (R9-R15 all null) -- but R11's direct
// profile shows WRITE_SIZE=153 MB vs 64.5 MB payload (2.4x inflation).
// The one never-varied component: the epilogue's ~262k scalar nt dword
// stores (64B lane-runs at 512B stride, L2-bypassed). nt partial-line
// writes draining at low effective BW backpressure the store queue and
// stall waves -- a mechanism that is occupancy-, placement-, register-
// and I$-invariant, exactly matching the null ledger. Change (one
// theory): drop nontemporal from gat_attn's num/acc stores and from
// gat_combine's num loads; let the 64 MB round-trip use L2.
// Base: R13 (best, 431.9us): LDS B-tile staging, 64 rows/wave,
// launch_bounds(256,2), grid 512, jsplit 16.

#define NN 8192
#define DIN 256
#define DOUT 128
#define LOG2E 1.4426950408889634f

typedef __attribute__((ext_vector_type(8))) short short8;   // 8 bf16 = 4 VGPRs (MFMA A/B frag)
typedef __attribute__((ext_vector_type(4))) float floatx4;  // MFMA C/D frag

// ---------------- kernel 0: W [256][128] fp32 -> WT [128][256] bf16 ----------------
__global__ void prep_wt(const float* __restrict__ W, __hip_bfloat16* __restrict__ WT) {
    int e = blockIdx.x * blockDim.x + threadIdx.x;
    if (e < DIN * DOUT) {
        int k = e >> 7;
        int d = e & 127;
        WT[d * DIN + k] = __float2bfloat16(W[e]);
    }
}

// ---------------- kernel 1: h = x@W + bW (MFMA), fused s_src/s_dst; h -> hbB frag-tile layout ----------------
// hbB flat index for h-element (row i, dim d):
//   g=i>>5, k=i&31, f=d>>4, n=d&15 -> g*4096 + f*512 + (k>>3)*128 + n*8 + (k&7)
__global__ __launch_bounds__(256, 4) void gat_h(
    const float* __restrict__ x, const __hip_bfloat16* __restrict__ WT,
    const float* __restrict__ bW, const float* __restrict__ a1, const float* __restrict__ a2,
    __hip_bfloat16* __restrict__ hbB, float* __restrict__ s_src, float* __restrict__ s_dst) {
    int tid = threadIdx.x;
    int w = tid >> 6, lane = tid & 63;
    int lm = lane & 15, lq = lane >> 4;
    int i0 = blockIdx.x * 32;
    int r0 = (w >> 1) * 16;
    int c0 = (w & 1) * 64;

    __shared__ float s1s[32], s2s[32];
    if (tid < 32) { s1s[tid] = 0.f; s2s[tid] = 0.f; }
    __syncthreads();

    floatx4 acc[4] = {};
#pragma unroll
    for (int kk = 0; kk < DIN; kk += 32) {
        const float4* xp = (const float4*)&x[(size_t)(i0 + r0 + lm) * DIN + kk + lq * 8];
        float4 xa = xp[0], xb = xp[1];
        union { short8 v; __hip_bfloat16 h[8]; } af;
        af.h[0] = __float2bfloat16(xa.x); af.h[1] = __float2bfloat16(xa.y);
        af.h[2] = __float2bfloat16(xa.z); af.h[3] = __float2bfloat16(xa.w);
        af.h[4] = __float2bfloat16(xb.x); af.h[5] = __float2bfloat16(xb.y);
        af.h[6] = __float2bfloat16(xb.z); af.h[7] = __float2bfloat16(xb.w);
#pragma unroll
        for (int t = 0; t < 4; t++) {
            int d = c0 + 16 * t + lm;
            short8 bf = *(const short8*)&WT[(size_t)d * DIN + kk + lq * 8];
            acc[t] = __builtin_amdgcn_mfma_f32_16x16x32_bf16(af.v, bf, acc[t], 0, 0, 0);
        }
    }
    float s1[4] = {0.f, 0.f, 0.f, 0.f}, s2[4] = {0.f, 0.f, 0.f, 0.f};
#pragma unroll
    for (int t = 0; t < 4; t++) {
        int d = c0 + 16 * t + lm;
        int f = (c0 >> 4) + t;
        float A1 = a1[d], A2 = a2[d], B = bW[d];
#pragma unroll
        for (int r = 0; r < 4; r++) {
            int k = r0 + lq * 4 + r;
            float h = acc[t][r] + B;
            hbB[(size_t)blockIdx.x * 4096 + f * 512 + (k >> 3) * 128 + lm * 8 + (k & 7)] =
                __float2bfloat16(h);
            s1[r] += h * A1;
            s2[r] += h * A2;
        }
    }
#pragma unroll
    for (int r = 0; r < 4; r++) {
        for (int m = 1; m < 16; m <<= 1) {
            s1[r] += __shfl_xor(s1[r], m, 64);
            s2[r] += __shfl_xor(s2[r], m, 64);
        }
    }
    if (lm == 0) {
#pragma unroll
        for (int r = 0; r < 4; r++) {
            int row = r0 + lq * 4 + r;
            atomicAdd(&s1s[row], s1[r]);
            atomicAdd(&s2s[row], s2[r]);
        }
    }
    __syncthreads();
    if (tid < 32) {
        s_src[i0 + tid] = s1s[tid] * LOG2E;   // pre-scale: exp(e) = exp2(e*log2e)
        s_dst[i0 + tid] = s2s[tid] * LOG2E;
    }
}

// ---------------- kernel 2: adj -> 1-bit mask, lane-permuted layout ----------------
// Contiguous (TLB/coalesce-friendly) read of the 268 MB adj stream; byte-group
// g of each 64-byte group permuted so gat_attn lane's NJT bytes are contiguous.
template <int NJT>
__global__ void build_mask(const int* __restrict__ adj, unsigned char* __restrict__ mask) {
    size_t gid = (size_t)blockIdx.x * blockDim.x + threadIdx.x;  // 8,388,608 threads
    const int4* a = (const int4*)(adj + gid * 8);
    int4 v0 = a[0], v1 = a[1];
    unsigned int b = 0;
    b |= (v0.x != 0) ? 1u : 0u;
    b |= (v0.y != 0) ? 2u : 0u;
    b |= (v0.z != 0) ? 4u : 0u;
    b |= (v0.w != 0) ? 8u : 0u;
    b |= (v1.x != 0) ? 16u : 0u;
    b |= (v1.y != 0) ? 32u : 0u;
    b |= (v1.z != 0) ? 64u : 0u;
    b |= (v1.w != 0) ? 128u : 0u;
    unsigned int g = (unsigned int)gid & (NJT * 4 - 1);
    size_t pos = (gid & ~(size_t)(NJT * 4 - 1)) | ((g & 3) * NJT + (g >> 2));
    mask[pos] = (unsigned char)b;
}

__device__ inline short8 make_pfrag(unsigned int cm, float ssi, float4 cd0, float4 cd1,
                                    floatx4* accd, const short8 ones) {
    float p[8];
    float e;
    e = ssi + cd0.x; e = fmaxf(e, 0.01f * e); p[0] = (cm & 1u)   ? __builtin_amdgcn_exp2f(e) : 0.f;
    e = ssi + cd0.y; e = fmaxf(e, 0.01f * e); p[1] = (cm & 2u)   ? __builtin_amdgcn_exp2f(e) : 0.f;
    e = ssi + cd0.z; e = fmaxf(e, 0.01f * e); p[2] = (cm & 4u)   ? __builtin_amdgcn_exp2f(e) : 0.f;
    e = ssi + cd0.w; e = fmaxf(e, 0.01f * e); p[3] = (cm & 8u)   ? __builtin_amdgcn_exp2f(e) : 0.f;
    e = ssi + cd1.x; e = fmaxf(e, 0.01f * e); p[4] = (cm & 16u)  ? __builtin_amdgcn_exp2f(e) : 0.f;
    e = ssi + cd1.y; e = fmaxf(e, 0.01f * e); p[5] = (cm & 32u)  ? __builtin_amdgcn_exp2f(e) : 0.f;
    e = ssi + cd1.z; e = fmaxf(e, 0.01f * e); p[6] = (cm & 64u)  ? __builtin_amdgcn_exp2f(e) : 0.f;
    e = ssi + cd1.w; e = fmaxf(e, 0.01f * e); p[7] = (cm & 128u) ? __builtin_amdgcn_exp2f(e) : 0.f;
    union { short8 v; __hip_bfloat162 q[4]; } af;
    af.q[0] = __float22bfloat162_rn(make_float2(p[0], p[1]));
    af.q[1] = __float22bfloat162_rn(make_float2(p[2], p[3]));
    af.q[2] = __float22bfloat162_rn(make_float2(p[4], p[5]));
    af.q[3] = __float22bfloat162_rn(make_float2(p[6], p[7]));
    *accd = __builtin_amdgcn_mfma_f32_16x16x32_bf16(af.v, ones, *accd, 0, 0, 0);
    return af.v;
}

// ---------------- kernel 3: masked softmax-weighted GEMM, 64 rows/wave, LDS B-tile ----------------
// grid = 32 row-blocks (256 rows) x JSPLIT. Wave w: rows i0=ib*256+w*64 .. +63
// as FOUR A-frag row-groups sharing each B-frag; all 128 dims.
// B-tile (8 frags x 512 bf16 = 8 KB) staged once per block into LDS,
// triple-buffered; one raw s_barrier + vmcnt(2) per t. Epilogue stores are
// PLAIN (cached) -- R16 change.
template <int NJT>
__global__ __launch_bounds__(256, 2) void gat_attn(
    const unsigned char* __restrict__ mask, const float* __restrict__ s_src,
    const float* __restrict__ s_dst, const float* __restrict__ ba_p,
    const __hip_bfloat16* __restrict__ hbB,
    float* __restrict__ num, float* __restrict__ lpart) {
    int tid = threadIdx.x;
    int w = tid >> 6, lane = tid & 63;
    int lm = lane & 15, lq = lane >> 4;
    int b = blockIdx.x;
    int ib = b & 31;
    int jh = b >> 5;
    int i0 = ib * 256 + w * 64;
    int jb0 = jh * (NJT * 32);

    __shared__ short8 bbuf[3][512];      // 24 KB: triple-buffered 8 KB B-tile
    __shared__ float sdl[NJT * 32];      // s_dst slice (2-4 KB)

    // per-lane mask slices for 4 row-groups: NJT contiguous bytes each
    union Mr { uint4 v[NJT / 16]; unsigned int u[NJT / 4]; };
    Mr mr[4];
    const unsigned char* mrow = mask + (size_t)(i0 + lm) * (NN / 8) + jh * (NJT * 4) + lq * NJT;
#pragma unroll
    for (int rg = 0; rg < 4; rg++)
#pragma unroll
        for (int q = 0; q < NJT / 16; q++)
            mr[rg].v[q] = ((const uint4*)(mrow + (size_t)rg * 16 * (NN / 8)))[q];

    float ba = ba_p[0] * LOG2E;
    float ssi[4];
#pragma unroll
    for (int rg = 0; rg < 4; rg++) ssi[rg] = s_src[i0 + rg * 16 + lm] + ba;

    const char* hb0 = (const char*)hbB + (size_t)jh * NJT * 8192;

#define STAGE(tt, p)                                                                 \
    do {                                                                             \
        const char* g_ = hb0 + (size_t)(tt) * 8192 + tid * 16;                       \
        char* l_ = (char*)&bbuf[p][0] + tid * 16;                                    \
        __builtin_amdgcn_global_load_lds(                                            \
            (const __attribute__((address_space(1))) unsigned int*)g_,               \
            (__attribute__((address_space(3))) unsigned int*)l_, 16, 0, 0);          \
        __builtin_amdgcn_global_load_lds(                                            \
            (const __attribute__((address_space(1))) unsigned int*)(g_ + 4096),      \
            (__attribute__((address_space(3))) unsigned int*)(l_ + 4096), 16, 0, 0); \
    } while (0)

    STAGE(0, 0);
    const float* sdg = s_dst + jb0;
    for (int k = tid; k < NJT * 32; k += 256) sdl[k] = sdg[k];
    __syncthreads();   // prologue only: full drain ok (tile 0 + sdl ready)

    floatx4 acc[4][8] = {};
    floatx4 accd[4] = {};
    const short8 ones = { 0x3F80, 0x3F80, 0x3F80, 0x3F80, 0x3F80, 0x3F80, 0x3F80, 0x3F80 };

#pragma unroll
    for (int t = 0; t < NJT; t++) {
        if (t + 1 < NJT) {
            STAGE(t + 1, (t + 1) % 3);
            asm volatile("s_waitcnt vmcnt(2)" ::: "memory");   // tile t landed; t+1 in flight
        } else {
            asm volatile("s_waitcnt vmcnt(0)" ::: "memory");
        }
        __builtin_amdgcn_s_barrier();
        __builtin_amdgcn_sched_barrier(0);

        float4 cd0 = *(const float4*)&sdl[t * 32 + lq * 8];
        float4 cd1 = *(const float4*)&sdl[t * 32 + lq * 8 + 4];
        short8 af[4];
#pragma unroll
        for (int rg = 0; rg < 4; rg++) {
            unsigned int cm = (mr[rg].u[t >> 2] >> ((t & 3) * 8)) & 0xFFu;
            af[rg] = make_pfrag(cm, ssi[rg], cd0, cd1, &accd[rg], ones);
        }
#pragma unroll
        for (int f = 0; f < 8; f++) {
            short8 bf = bbuf[t % 3][f * 64 + lane];
#pragma unroll
            for (int rg = 0; rg < 4; rg++)
                acc[rg][f] = __builtin_amdgcn_mfma_f32_16x16x32_bf16(af[rg], bf, acc[rg][f], 0, 0, 0);
        }
    }
#undef STAGE

    // epilogue: C/D layout col(dim-part)=lm, row=lq*4+r. PLAIN stores (R16):
    // nt partial-line writes showed 2.4x WRITE inflation (R11: 153 vs 64.5 MB)
    // and are the prime suspect for the occupancy/placement-invariant stall.
    float* nb = num + ((size_t)jh * NN + i0) * DOUT;
#pragma unroll
    for (int rg = 0; rg < 4; rg++)
#pragma unroll
        for (int f = 0; f < 8; f++)
#pragma unroll
            for (int r = 0; r < 4; r++)
                nb[(size_t)(rg * 16 + lq * 4 + r) * DOUT + f * 16 + lm] = acc[rg][f][r];
    if (lm == 0) {
#pragma unroll
        for (int rg = 0; rg < 4; rg++)
#pragma unroll
            for (int r = 0; r < 4; r++)
                lpart[(size_t)jh * NN + i0 + rg * 16 + lq * 4 + r] = accd[rg][r];
    }
}

// ---------------- kernel 4: combine partials, divide ----------------
__global__ void gat_combine(const float* __restrict__ num, const float* __restrict__ lpart,
                            float* __restrict__ out, int jsplit) {
    int gid = blockIdx.x * blockDim.x + threadIdx.x;  // 262144 threads, one float4 each
    int idx = gid * 4;
    int i = idx >> 7;
    float den = 0.f;
    for (int s = 0; s < jsplit; s++) den += lpart[(size_t)s * NN + i];
    float inv = 1.0f / den;
    floatx4 o = {0.f, 0.f, 0.f, 0.f};
    for (int s = 0; s < jsplit; s++) {
        floatx4 n = *(const floatx4*)&num[(size_t)s * NN * DOUT + idx];
        o += n;
    }
    o *= inv;
    *(floatx4*)&out[idx] = o;
}

extern "C" void kernel_launch(void* const* d_in, const int* in_sizes, int n_in,
                              void* d_out, int out_size, void* d_ws, size_t ws_size,
                              hipStream_t stream) {
    const float* x  = (const float*)d_in[0];
    const int* adj  = (const int*)d_in[1];
    const float* W  = (const float*)d_in[2];
    const float* bW = (const float*)d_in[3];
    const float* a1 = (const float*)d_in[4];
    const float* a2 = (const float*)d_in[5];
    const float* ba = (const float*)d_in[6];
    float* out = (float*)d_out;

    char* ws = (char*)d_ws;
    __hip_bfloat16* hbB  = (__hip_bfloat16*)ws;                    // 2 MB   frag-tile layout
    __hip_bfloat16* WT   = (__hip_bfloat16*)(ws + 2097152);        // 64 KB
    float* s_src         = (float*)(ws + 2162688);                 // 32 KB (pre-scaled by log2e)
    float* s_dst         = (float*)(ws + 2195456);                 // 32 KB (pre-scaled by log2e)
    float* lpart         = (float*)(ws + 2228224);                 // 512 KB [<=16][8192]
    unsigned char* mask  = (unsigned char*)(ws + 2752512);         // 8 MB   permuted
    float* num           = (float*)(ws + 11141120);                // jsplit*4 MB

    int jsplit = (ws_size >= 11141120 + (size_t)16 * NN * DOUT * 4) ? 16 : 8;

    // build_mask first: keeps gat_h's outputs (hbB/s_dst) L2-warm for gat_attn.
    if (jsplit == 16) build_mask<16><<<32768, 256, 0, stream>>>(adj, mask);
    else              build_mask<32><<<32768, 256, 0, stream>>>(adj, mask);
    prep_wt<<<128, 256, 0, stream>>>(W, WT);
    gat_h<<<256, 256, 0, stream>>>(x, WT, bW, a1, a2, hbB, s_src, s_dst);
    if (jsplit == 16)
        gat_attn<16><<<512, 256, 0, stream>>>(mask, s_src, s_dst, ba, hbB, num, lpart);
    else
        gat_attn<32><<<256, 256, 0, stream>>>(mask, s_src, s_dst, ba, hbB, num, lpart);
    gat_combine<<<1024, 256, 0, stream>>>(num, lpart, out, jsplit);
}